// Round 5
// baseline (219.412 us; speedup 1.0000x reference)
//
#include <hip/hip_runtime.h>

#define LR 0.01f
#define EPS 1e-10f

typedef float f32x4 __attribute__((ext_vector_type(4)));

// Inputs: idx (N, int32), grad (N,64 f32), state (V,64 f32), emb (V,64 f32)
// Outputs concatenated: new_state (V*64 f32) then new_emb (V*64 f32)
// Scratch: head[V] int32 (4 MB) + next[N] int32 (1 MB) in d_ws
//
// Chain-gather strategy (R3) + R4 streaming tuning:
//  - head init via hipMemsetAsync(0xFF) == -1
//  - branchless fused pass: untouched rows are the c==0 / mean==0 special
//    case of the update (new_state = s exactly, new_emb = e exactly)
//  - nontemporal loads for state/emb and nontemporal stores for outputs
//    (read-once/write-once streams; don't pollute L2/L3) — native clang
//    vector type, since the builtin rejects HIP_vector_type
//  - grid-stride loop, 4096 blocks x 256

__global__ void link_kernel(const int* __restrict__ idx,
                            int* __restrict__ head,
                            int* __restrict__ next, int N) {
    int i = blockIdx.x * blockDim.x + threadIdx.x;
    if (i >= N) return;
    next[i] = atomicExch(&head[idx[i]], i);
}

// 16 threads per vocab row (each handles one float4 of the 64-wide row).
__global__ void fused_kernel(const float* __restrict__ state,
                             const float* __restrict__ emb,
                             const float* __restrict__ grad,
                             const int* __restrict__ head,
                             const int* __restrict__ next,
                             float* __restrict__ out_state,
                             float* __restrict__ out_emb, long long total) {
    long long stride = (long long)gridDim.x * blockDim.x;
    for (long long t = (long long)blockIdx.x * blockDim.x + threadIdx.x;
         t < total; t += stride) {
        long long row = t >> 4;
        int q = (int)(t & 15);
        size_t off = (size_t)row * 64 + (size_t)q * 4;

        int h = head[row];
        f32x4 s = __builtin_nontemporal_load(reinterpret_cast<const f32x4*>(state + off));
        f32x4 e = __builtin_nontemporal_load(reinterpret_cast<const f32x4*>(emb + off));

        // gather grad rows along the chain (0 iterations for untouched rows)
        float sum0 = 0.f, sum1 = 0.f, sum2 = 0.f, sum3 = 0.f;
        int c = 0;
        for (int j = h; j >= 0; j = next[j]) {
            const f32x4 g = *reinterpret_cast<const f32x4*>(grad + (size_t)j * 64 + (size_t)q * 4);
            sum0 += g.x; sum1 += g.y; sum2 += g.z; sum3 += g.w;
            ++c;
        }
        // c==0: inv=0 -> mean=0 -> new_state==s, new_emb==e (exact)
        float inv = (c > 0) ? (1.0f / (float)c) : 0.0f;
        float m0 = sum0 * inv, m1 = sum1 * inv, m2 = sum2 * inv, m3 = sum3 * inv;
        float s0 = s.x + m0 * m0, s1 = s.y + m1 * m1;
        float s2 = s.z + m2 * m2, s3 = s.w + m3 * m3;
        f32x4 ns = { s0, s1, s2, s3 };
        f32x4 ne = { e.x - LR * m0 / (sqrtf(s0) + EPS),
                     e.y - LR * m1 / (sqrtf(s1) + EPS),
                     e.z - LR * m2 / (sqrtf(s2) + EPS),
                     e.w - LR * m3 / (sqrtf(s3) + EPS) };
        __builtin_nontemporal_store(ns, reinterpret_cast<f32x4*>(out_state + off));
        __builtin_nontemporal_store(ne, reinterpret_cast<f32x4*>(out_emb + off));
    }
}

extern "C" void kernel_launch(void* const* d_in, const int* in_sizes, int n_in,
                              void* d_out, int out_size, void* d_ws, size_t ws_size,
                              hipStream_t stream) {
    const int* idx = (const int*)d_in[0];
    const float* grad = (const float*)d_in[1];
    const float* state = (const float*)d_in[2];
    const float* emb = (const float*)d_in[3];

    int N = in_sizes[0];
    int D = in_sizes[1] / N;         // expected 64
    long long VD = in_sizes[2];
    int V = (int)(VD / D);

    float* out_state = (float*)d_out;
    float* out_emb = (float*)d_out + (size_t)V * D;
    int* head = (int*)d_ws;                    // V ints
    int* next = (int*)d_ws + V;                // N ints

    const int threads = 256;

    // 1. head = -1 via memset (graph-capture-safe async memset)
    (void)hipMemsetAsync(head, 0xFF, (size_t)V * sizeof(int), stream);

    // 2. build chains (int atomics on 4 MB L2-hot region)
    link_kernel<<<(N + threads - 1) / threads, threads, 0, stream>>>(idx, head, next, N);

    // 3. fused streaming pass: gather+update (or exact copy when c==0)
    {
        long long total = (long long)V * 16;
        int blocks = 4096;
        fused_kernel<<<blocks, threads, 0, stream>>>(state, emb, grad, head, next,
                                                     out_state, out_emb, total);
    }
}